// Round 6
// baseline (682.909 us; speedup 1.0000x reference)
//
#include <hip/hip_runtime.h>

#define C128 128

typedef __attribute__((ext_vector_type(2))) float f32x2;
typedef __attribute__((ext_vector_type(4))) float f32x4;
typedef __attribute__((ext_vector_type(8))) short short8;

// f32 -> bf16 round-to-nearest-even (finite inputs)
__device__ __forceinline__ short f2bf(float f) {
  union { float f; unsigned u; } v; v.f = f;
  unsigned r = (v.u + 0x7fffu + ((v.u >> 16) & 1u)) >> 16;
  return (short)r;
}

// out[r][j] = sum_k A[r][k]*W[j][k] (+add[r][j]) (+gtab[gidx[r]][j])
// 64 rows/block, 4 waves, wave owns 16 rows x 128 cols. MFMA 16x16x32 bf16.
// In-place safe for out==A (wave reads only the 16 rows it writes; reads precede stores).
__device__ __forceinline__ void gemm_body(
    const float* __restrict__ A, const float* __restrict__ W,
    const float* __restrict__ add,
    const int* __restrict__ gidx, const float* __restrict__ gtab,
    float* __restrict__ out, int R, int blockrow)
{
  const int tid  = threadIdx.x;
  const int wave = tid >> 6;
  const int lane = tid & 63;
  const int r16  = lane & 15;
  const int kg   = lane >> 4;

  const int rowbase = blockrow + wave * 16;
  if (rowbase >= R) return;
  const int arow_i  = rowbase + r16;
  const int lrow    = arow_i < R ? arow_i : (R - 1);  // clamp; garbage never stored

  f32x4 acc[8];
#pragma unroll
  for (int i = 0; i < 8; ++i) acc[i] = (f32x4){0.f, 0.f, 0.f, 0.f};

  const float* arow = A + (long long)lrow * C128;

#pragma unroll
  for (int ks = 0; ks < 4; ++ks) {
    const int k0 = ks * 32 + kg * 8;
    f32x4 alo = *(const f32x4*)(arow + k0);
    f32x4 ahi = *(const f32x4*)(arow + k0 + 4);
    short8 af;
    af[0] = f2bf(alo.x); af[1] = f2bf(alo.y);
    af[2] = f2bf(alo.z); af[3] = f2bf(alo.w);
    af[4] = f2bf(ahi.x); af[5] = f2bf(ahi.y);
    af[6] = f2bf(ahi.z); af[7] = f2bf(ahi.w);
#pragma unroll
    for (int nf = 0; nf < 8; ++nf) {
      const float* wrow = W + (nf * 16 + r16) * C128 + k0;
      f32x4 wlo = *(const f32x4*)(wrow);
      f32x4 whi = *(const f32x4*)(wrow + 4);
      short8 bf;
      bf[0] = f2bf(wlo.x); bf[1] = f2bf(wlo.y);
      bf[2] = f2bf(wlo.z); bf[3] = f2bf(wlo.w);
      bf[4] = f2bf(whi.x); bf[5] = f2bf(whi.y);
      bf[6] = f2bf(whi.z); bf[7] = f2bf(whi.w);
      acc[nf] = __builtin_amdgcn_mfma_f32_16x16x32_bf16(af, bf, acc[nf], 0, 0, 0);
    }
  }

#pragma unroll
  for (int i = 0; i < 4; ++i) {
    const int orow = rowbase + kg * 4 + i;
    if (orow >= R) continue;
    const float* addrow = add ? add + (long long)orow * C128 : nullptr;
    const float* grow = gidx ? gtab + (long long)gidx[orow] * C128 : nullptr;
    float* orow_p = out + (long long)orow * C128;
#pragma unroll
    for (int nf = 0; nf < 8; ++nf) {
      const int oc = nf * 16 + r16;
      float v = acc[nf][i];
      if (addrow) v += addrow[oc];
      if (grow)   v += grow[oc];
      orow_p[oc] = v;
    }
  }
}

// pre: zero the counter region, then t1 = x1@W1^T / t2 = x2@W2^T
__global__ __launch_bounds__(256) void pre_gemm(
    const float* __restrict__ x1, const float* __restrict__ W1, float* __restrict__ t1, int n1,
    const float* __restrict__ x2, const float* __restrict__ W2, float* __restrict__ t2, int n2,
    int* __restrict__ zbuf, int zlen, int B1)
{
  {
    const int nb  = gridDim.x;
    const int per = (zlen + nb - 1) / nb;
    const int zs  = blockIdx.x * per;
    const int ze  = (zs + per < zlen) ? zs + per : zlen;
    for (int k = zs + threadIdx.x; k < ze; k += 256) zbuf[k] = 0;
  }
  if ((int)blockIdx.x < B1)
    gemm_body(x1, W1, nullptr, nullptr, nullptr, t1, n1, blockIdx.x * 64);
  else
    gemm_body(x2, W2, nullptr, nullptr, nullptr, t2, n2, (blockIdx.x - B1) * 64);
}

// post: y1 = mean0@Wa^T + x1 + t2[cluster2] ; y2 = mean1@Wb^T + x2 (in-place A==out)
__global__ __launch_bounds__(256) void post_gemm(
    const float* __restrict__ mean0, const float* __restrict__ Wa,
    const float* __restrict__ x1, const int* __restrict__ cluster2,
    const float* __restrict__ t2, float* __restrict__ y1, int n1,
    const float* __restrict__ mean1, const float* __restrict__ Wb,
    const float* __restrict__ x2, float* __restrict__ y2, int n2, int B1)
{
  if ((int)blockIdx.x < B1)
    gemm_body(mean0, Wa, x1, cluster2, t2, y1, n1, blockIdx.x * 64);
  else
    gemm_body(mean1, Wb, x2, nullptr, nullptr, y2, n2, (blockIdx.x - B1) * 64);
}

// merged histogram over both cluster arrays
__global__ __launch_bounds__(256) void hist2(
    const int* __restrict__ cl1, int n0, int* __restrict__ cnt0,
    const int* __restrict__ cl2, int n1, int* __restrict__ cnt1)
{
  int i = blockIdx.x * blockDim.x + threadIdx.x;
  const int stride = gridDim.x * blockDim.x;
  const int total = n0 + n1;
  for (; i < total; i += stride) {
    if (i < n0) atomicAdd(&cnt0[cl1[i]], 1);
    else        atomicAdd(&cnt1[cl2[i - n0]], 1);
  }
}

// merged offsets: wave-prefix-scan + one atomic per wave on the region cursor.
__global__ __launch_bounds__(256) void scan2(
    const int* __restrict__ cnt0, int* __restrict__ off0, int* __restrict__ cur0, int n1,
    const int* __restrict__ cnt1, int* __restrict__ off1, int* __restrict__ cur1, int n2,
    int* __restrict__ tot)
{
  const int p1 = (n1 + 255) & ~255;
  const int i  = blockIdx.x * blockDim.x + threadIdx.x;
  const int lane = threadIdx.x & 63;

  const int* cnt; int* off; int* cur; int* t; int j; int nn;
  if (i < p1) { cnt = cnt0; off = off0; cur = cur0; t = tot + 0; j = i;      nn = n1; }
  else        { cnt = cnt1; off = off1; cur = cur1; t = tot + 1; j = i - p1; nn = n2; }

  int c = (j < nn) ? cnt[j] : 0;
  int pref = c;
#pragma unroll
  for (int d = 1; d < 64; d <<= 1) {
    int v = __shfl_up(pref, d);
    if (lane >= d) pref += v;
  }
  const int wave_total = __shfl(pref, 63);
  int base = 0;
  if (lane == 63) base = atomicAdd(t, wave_total);
  base = __shfl(base, 63);

  if (j < nn) {
    const int o = base + (pref - c);
    off[j] = o;
    cur[j] = o;
  }
}

// merged member-list fill
__global__ __launch_bounds__(256) void fill2(
    const int* __restrict__ cl1, int n0, int* __restrict__ cur0, int* __restrict__ idx0,
    const int* __restrict__ cl2, int n1, int* __restrict__ cur1, int* __restrict__ idx1)
{
  int i = blockIdx.x * blockDim.x + threadIdx.x;
  const int stride = gridDim.x * blockDim.x;
  const int total = n0 + n1;
  for (; i < total; i += stride) {
    if (i < n0) { int p = atomicAdd(&cur0[cl1[i]], 1); idx0[p] = i; }
    else        { int k = i - n0; int p = atomicAdd(&cur1[cl2[k]], 1); idx1[p] = k; }
  }
}

// SEQUENTIAL pass: y0[row] = x0[row] + t1[cluster1[row]].
// One thread = one f32x4 (32 threads/row). x0 read + y0 write fully sequential;
// t1 gather random 512B rows within 51MB (L3-resident).
__global__ __launch_bounds__(256) void stream_y0(
    const float* __restrict__ x0, const int* __restrict__ cl1,
    const float* __restrict__ t1, float* __restrict__ y0, long long nvec)
{
  long long i = (long long)blockIdx.x * blockDim.x + threadIdx.x;
  const long long stride = (long long)gridDim.x * blockDim.x;
  for (; i < nvec; i += stride) {
    const long long row = i >> 5;
    const int q = (int)(i & 31);
    const int c = cl1[row];
    f32x4 xv = ((const f32x4*)x0)[i];
    f32x4 tv = ((const f32x4*)t1)[(long long)c * 32 + q];
    ((f32x4*)y0)[i] = xv + tv;
  }
}

// CSR gather means, READ-ONLY random traffic. One wave per cluster; the two
// 32-lane halves each load a full 512B row (f32x4 per lane), 2x unrolled =
// 4 row-loads in flight per wave. wid < n1: x0 -> mean0; else x1 -> mean1.
__global__ __launch_bounds__(256) void gather_mean(
    const float* __restrict__ x0, const int* __restrict__ idx0,
    const int* __restrict__ off0, const int* __restrict__ cnt0,
    float* __restrict__ mean0, int n1,
    const float* __restrict__ x1, const int* __restrict__ idx1,
    const int* __restrict__ off1, const int* __restrict__ cnt1,
    float* __restrict__ mean1, int n2)
{
  int wid = blockIdx.x * 4 + (threadIdx.x >> 6);
  const int lane = threadIdx.x & 63;
  const int half = lane >> 5;
  const int l32  = lane & 31;
  if (wid >= n1 + n2) return;

  const float* x; const int* idxp; const int* offp; const int* cntp; float* meanp;
  if (wid < n1) { x = x0; idxp = idx0; offp = off0; cntp = cnt0; meanp = mean0; }
  else { wid -= n1; x = x1; idxp = idx1; offp = off1; cntp = cnt1; meanp = mean1; }

  const int n = cntp[wid];
  const int o = offp[wid];

  f32x4 s0 = {0.f,0.f,0.f,0.f}, s1 = {0.f,0.f,0.f,0.f};

  for (int base = 0; base < n; base += 64) {
    const int m = (n - base < 64) ? (n - base) : 64;
    int vi = (lane < m) ? idxp[o + base + lane] : 0;
    int j = 0;
    for (; j + 3 < m; j += 4) {
      const long long ia = __shfl(vi, j + half);
      const long long ib = __shfl(vi, j + 2 + half);
      f32x4 a = ((const f32x4*)(x + ia * C128))[l32];
      f32x4 b = ((const f32x4*)(x + ib * C128))[l32];
      s0 += a; s1 += b;
    }
    for (; j + 1 < m; j += 2) {
      const long long ia = __shfl(vi, j + half);
      s0 += ((const f32x4*)(x + ia * C128))[l32];
    }
    if (j < m) {  // single leftover member: half 0 only
      const long long ia = __shfl(vi, j);
      if (half == 0) s0 += ((const f32x4*)(x + ia * C128))[l32];
    }
  }

  f32x4 s = s0 + s1;
  // combine the two half-wave partials (both cover all 128 cols)
  f32x4 t;
  t[0] = __shfl_xor(s[0], 32); t[1] = __shfl_xor(s[1], 32);
  t[2] = __shfl_xor(s[2], 32); t[3] = __shfl_xor(s[3], 32);
  s += t;

  const float invn = n > 0 ? 1.0f / (float)n : 0.0f;
  if (half == 0)
    ((f32x4*)(meanp + (long long)wid * C128))[l32] = s * invn;
}

extern "C" void kernel_launch(void* const* d_in, const int* in_sizes, int n_in,
                              void* d_out, int out_size, void* d_ws, size_t ws_size,
                              hipStream_t stream)
{
  const float* x0 = (const float*)d_in[0];
  const float* x1 = (const float*)d_in[1];
  const float* x2 = (const float*)d_in[2];
  const int* cluster1 = (const int*)d_in[3];
  const int* cluster2 = (const int*)d_in[4];
  const float* Wf2c0 = (const float*)d_in[5];
  const float* Wf2c1 = (const float*)d_in[6];
  const float* Wc2f0 = (const float*)d_in[7];
  const float* Wc2f1 = (const float*)d_in[8];

  const int N0 = in_sizes[0] / C128;
  const int N1 = in_sizes[1] / C128;
  const int N2 = in_sizes[2] / C128;

  float* y0 = (float*)d_out;
  float* y1 = y0 + (long long)N0 * C128;
  float* y2 = y1 + (long long)N1 * C128;

  // means in-place in output regions (post_gemm is in-place safe)
  float* mean0 = y1;
  float* mean1 = y2;

  // ws: [t1: N1*128][t2: N2*128][cnt0: N1][cnt1: N2][tot: 2][off0: N1][off1: N2]
  //     [cur0: N1][cur1: N2][idx0: N0][idx1: N1]
  float* t1 = (float*)d_ws;
  float* t2 = t1 + (long long)N1 * C128;
  int* cnt0 = (int*)(t2 + (long long)N2 * C128);
  int* cnt1 = cnt0 + N1;
  int* tot  = cnt1 + N2;
  int* off0 = tot + 2;
  int* off1 = off0 + N1;
  int* cur0 = off1 + N2;
  int* cur1 = cur0 + N1;
  int* idx0 = cur1 + N2;
  int* idx1 = idx0 + N0;

  const int B1 = (N1 + 63) / 64;
  const int B2 = (N2 + 63) / 64;

  // 1. pre: zero cnt/cur/tot region + t1 = x1@Wc2f0^T, t2 = x2@Wc2f1^T
  pre_gemm<<<B1 + B2, 256, 0, stream>>>(
      x1, Wc2f0, t1, N1, x2, Wc2f1, t2, N2, cnt0, N1 + N2 + 2, B1);

  // 2-4. CSR build
  int bh = (N0 + N1 + 255) / 256; if (bh > 2048) bh = 2048;
  hist2<<<bh, 256, 0, stream>>>(cluster1, N0, cnt0, cluster2, N1, cnt1);
  const int p1 = (N1 + 255) & ~255, p2 = (N2 + 255) & ~255;
  scan2<<<(p1 + p2) / 256, 256, 0, stream>>>(
      cnt0, off0, cur0, N1, cnt1, off1, cur1, N2, tot);
  fill2<<<bh, 256, 0, stream>>>(cluster1, N0, cur0, idx0, cluster2, N1, cur1, idx1);

  // 5. sequential stream: y0 = x0 + t1[cluster1]
  stream_y0<<<2048, 256, 0, stream>>>(x0, cluster1, t1, y0, (long long)N0 * 32);

  // 6. read-only CSR gather: mean0 (from x0), mean1 (from x1)
  gather_mean<<<(N1 + N2 + 3) / 4, 256, 0, stream>>>(
      x0, idx0, off0, cnt0, mean0, N1,
      x1, idx1, off1, cnt1, mean1, N2);

  // 7. post: y1, y2
  post_gemm<<<B1 + B2, 256, 0, stream>>>(
      mean0, Wf2c0, x1, cluster2, t2, y1, N1,
      mean1, Wf2c1, x2, y2, N2, B1);
}

// Round 8
// 502.097 us; speedup vs baseline: 1.3601x; 1.3601x over previous
//
#include <hip/hip_runtime.h>

#define C128 128
#define WSTRIDE 136  // LDS W row stride in bf16 elements (128 + 8 pad -> 2-way bank alias, free)

typedef __attribute__((ext_vector_type(2))) float f32x2;
typedef __attribute__((ext_vector_type(4))) float f32x4;
typedef __attribute__((ext_vector_type(8))) short short8;

// f32 -> bf16 round-to-nearest-even (finite inputs)
__device__ __forceinline__ short f2bf(float f) {
  union { float f; unsigned u; } v; v.f = f;
  unsigned r = (v.u + 0x7fffu + ((v.u >> 16) & 1u)) >> 16;
  return (short)r;
}

// Convert 128x128 f32 W into LDS bf16 once per block (64 f2bf per thread).
__device__ __forceinline__ void stage_W(const float* __restrict__ W, ushort* Wl) {
  const int tid = threadIdx.x;
#pragma unroll
  for (int c = 0; c < 16; ++c) {
    const int e = (c * 256 + tid) * 4;          // element index, multiple of 4
    const int row = e >> 7, col = e & 127;
    f32x4 v = *(const f32x4*)(W + e);
    ushort4 u;
    u.x = (ushort)f2bf(v.x); u.y = (ushort)f2bf(v.y);
    u.z = (ushort)f2bf(v.z); u.w = (ushort)f2bf(v.w);
    *(ushort4*)(Wl + row * WSTRIDE + col) = u;
  }
}

// out[r][j] = sum_k A[r][k]*W[j][k] (+add[r][j]) (+gtab[gidx[r]][j])
// W pre-staged in LDS as bf16. One 64-row tile; 4 waves, wave owns 16 rows.
// In-place safe for out==A (wave reads only the 16 rows it writes).
__device__ __forceinline__ void gemm_body(
    const float* __restrict__ A, const ushort* __restrict__ Wl,
    const float* __restrict__ add,
    const int* __restrict__ gidx, const float* __restrict__ gtab,
    float* __restrict__ out, int R, int blockrow)
{
  const int tid  = threadIdx.x;
  const int wave = tid >> 6;
  const int lane = tid & 63;
  const int r16  = lane & 15;
  const int kg   = lane >> 4;

  const int rowbase = blockrow + wave * 16;
  if (rowbase >= R) return;
  const int arow_i  = rowbase + r16;
  const int lrow    = arow_i < R ? arow_i : (R - 1);  // clamp; garbage never stored

  f32x4 acc[8];
#pragma unroll
  for (int i = 0; i < 8; ++i) acc[i] = (f32x4){0.f, 0.f, 0.f, 0.f};

  const float* arow = A + (long long)lrow * C128;

#pragma unroll
  for (int ks = 0; ks < 4; ++ks) {
    const int k0 = ks * 32 + kg * 8;
    f32x4 alo = *(const f32x4*)(arow + k0);
    f32x4 ahi = *(const f32x4*)(arow + k0 + 4);
    short8 af;
    af[0] = f2bf(alo.x); af[1] = f2bf(alo.y);
    af[2] = f2bf(alo.z); af[3] = f2bf(alo.w);
    af[4] = f2bf(ahi.x); af[5] = f2bf(ahi.y);
    af[6] = f2bf(ahi.z); af[7] = f2bf(ahi.w);
#pragma unroll
    for (int nf = 0; nf < 8; ++nf) {
      short8 bf = *(const short8*)(Wl + (nf * 16 + r16) * WSTRIDE + k0);
      acc[nf] = __builtin_amdgcn_mfma_f32_16x16x32_bf16(af, bf, acc[nf], 0, 0, 0);
    }
  }

#pragma unroll
  for (int i = 0; i < 4; ++i) {
    const int orow = rowbase + kg * 4 + i;
    if (orow >= R) continue;
    const float* addrow = add ? add + (long long)orow * C128 : nullptr;
    const float* grow = gidx ? gtab + (long long)gidx[orow] * C128 : nullptr;
    float* orow_p = out + (long long)orow * C128;
#pragma unroll
    for (int nf = 0; nf < 8; ++nf) {
      const int oc = nf * 16 + r16;
      float v = acc[nf][i];
      if (addrow) v += addrow[oc];
      if (grow)   v += grow[oc];
      orow_p[oc] = v;
    }
  }
}

// pre: zero the counter region, then t1 = x1@W1^T / t2 = x2@W2^T
__global__ __launch_bounds__(256) void pre_gemm(
    const float* __restrict__ x1, const float* __restrict__ W1, float* __restrict__ t1, int n1,
    const float* __restrict__ x2, const float* __restrict__ W2, float* __restrict__ t2, int n2,
    int* __restrict__ zbuf, int zlen, int B1)
{
  __shared__ ushort Wl[C128 * WSTRIDE];
  {
    const int nb  = gridDim.x;
    const int per = (zlen + nb - 1) / nb;
    const int zs  = blockIdx.x * per;
    const int ze  = (zs + per < zlen) ? zs + per : zlen;
    for (int k = zs + threadIdx.x; k < ze; k += 256) zbuf[k] = 0;
  }
  if ((int)blockIdx.x < B1) {
    stage_W(W1, Wl); __syncthreads();
    gemm_body(x1, Wl, nullptr, nullptr, nullptr, t1, n1, blockIdx.x * 64);
  } else {
    stage_W(W2, Wl); __syncthreads();
    gemm_body(x2, Wl, nullptr, nullptr, nullptr, t2, n2, (blockIdx.x - B1) * 64);
  }
}

// post: y1 = mean0@Wa^T + x1 + t2[cluster2] ; y2 = mean1@Wb^T + x2 (in-place A==out)
__global__ __launch_bounds__(256) void post_gemm(
    const float* __restrict__ mean0, const float* __restrict__ Wa,
    const float* __restrict__ x1, const int* __restrict__ cluster2,
    const float* __restrict__ t2, float* __restrict__ y1, int n1,
    const float* __restrict__ mean1, const float* __restrict__ Wb,
    const float* __restrict__ x2, float* __restrict__ y2, int n2, int B1)
{
  __shared__ ushort Wl[C128 * WSTRIDE];
  if ((int)blockIdx.x < B1) {
    stage_W(Wa, Wl); __syncthreads();
    gemm_body(mean0, Wl, x1, cluster2, t2, y1, n1, blockIdx.x * 64);
  } else {
    stage_W(Wb, Wl); __syncthreads();
    gemm_body(mean1, Wl, x2, nullptr, nullptr, y2, n2, (blockIdx.x - B1) * 64);
  }
}

// merged histogram over both cluster arrays
__global__ __launch_bounds__(256) void hist2(
    const int* __restrict__ cl1, int n0, int* __restrict__ cnt0,
    const int* __restrict__ cl2, int n1, int* __restrict__ cnt1)
{
  int i = blockIdx.x * blockDim.x + threadIdx.x;
  const int stride = gridDim.x * blockDim.x;
  const int total = n0 + n1;
  for (; i < total; i += stride) {
    if (i < n0) atomicAdd(&cnt0[cl1[i]], 1);
    else        atomicAdd(&cnt1[cl2[i - n0]], 1);
  }
}

// merged offsets: wave-prefix-scan + one atomic per wave on the region cursor.
__global__ __launch_bounds__(256) void scan2(
    const int* __restrict__ cnt0, int* __restrict__ off0, int* __restrict__ cur0, int n1,
    const int* __restrict__ cnt1, int* __restrict__ off1, int* __restrict__ cur1, int n2,
    int* __restrict__ tot)
{
  const int p1 = (n1 + 255) & ~255;
  const int i  = blockIdx.x * blockDim.x + threadIdx.x;
  const int lane = threadIdx.x & 63;

  const int* cnt; int* off; int* cur; int* t; int j; int nn;
  if (i < p1) { cnt = cnt0; off = off0; cur = cur0; t = tot + 0; j = i;      nn = n1; }
  else        { cnt = cnt1; off = off1; cur = cur1; t = tot + 1; j = i - p1; nn = n2; }

  int c = (j < nn) ? cnt[j] : 0;
  int pref = c;
#pragma unroll
  for (int d = 1; d < 64; d <<= 1) {
    int v = __shfl_up(pref, d);
    if (lane >= d) pref += v;
  }
  const int wave_total = __shfl(pref, 63);
  int base = 0;
  if (lane == 63) base = atomicAdd(t, wave_total);
  base = __shfl(base, 63);

  if (j < nn) {
    const int o = base + (pref - c);
    off[j] = o;
    cur[j] = o;
  }
}

// merged member-list fill
__global__ __launch_bounds__(256) void fill2(
    const int* __restrict__ cl1, int n0, int* __restrict__ cur0, int* __restrict__ idx0,
    const int* __restrict__ cl2, int n1, int* __restrict__ cur1, int* __restrict__ idx1)
{
  int i = blockIdx.x * blockDim.x + threadIdx.x;
  const int stride = gridDim.x * blockDim.x;
  const int total = n0 + n1;
  for (; i < total; i += stride) {
    if (i < n0) { int p = atomicAdd(&cur0[cl1[i]], 1); idx0[p] = i; }
    else        { int k = i - n0; int p = atomicAdd(&cur1[cl2[k]], 1); idx1[p] = k; }
  }
}

// One cluster's fused gather: sum member rows (4 in flight), optional y-write,
// write mean. Lane owns columns {2*lane, 2*lane+1} (f32x2; 512B/row coalesced).
__device__ __forceinline__ void cr_one(
    int wid, int lane, const float* __restrict__ x,
    const int* __restrict__ idxp, const int* __restrict__ offp,
    const int* __restrict__ cntp, const float* __restrict__ trow,
    float* __restrict__ yb, float* __restrict__ meanp)
{
  const int n = cntp[wid];
  const int o = offp[wid];

  f32x2 tc = {0.f, 0.f};
  if (trow) tc = ((const f32x2*)trow)[lane];

  f32x2 s0 = {0.f,0.f}, s1 = {0.f,0.f}, s2 = {0.f,0.f}, s3 = {0.f,0.f};
  for (int base = 0; base < n; base += 64) {
    int m = n - base; if (m > 64) m = 64;
    int vi = (lane < m) ? idxp[o + base + lane] : 0;
    int j = 0;
    for (; j + 3 < m; j += 4) {
      const long long i0 = __shfl(vi, j);
      const long long i1 = __shfl(vi, j + 1);
      const long long i2 = __shfl(vi, j + 2);
      const long long i3 = __shfl(vi, j + 3);
      f32x2 a = ((const f32x2*)(x + i0 * C128))[lane];
      f32x2 b = ((const f32x2*)(x + i1 * C128))[lane];
      f32x2 c = ((const f32x2*)(x + i2 * C128))[lane];
      f32x2 d = ((const f32x2*)(x + i3 * C128))[lane];
      s0 += a; s1 += b; s2 += c; s3 += d;
      if (yb) {
        ((f32x2*)(yb + i0 * C128))[lane] = a + tc;
        ((f32x2*)(yb + i1 * C128))[lane] = b + tc;
        ((f32x2*)(yb + i2 * C128))[lane] = c + tc;
        ((f32x2*)(yb + i3 * C128))[lane] = d + tc;
      }
    }
    for (; j < m; ++j) {
      const long long i0 = __shfl(vi, j);
      f32x2 a = ((const f32x2*)(x + i0 * C128))[lane];
      s0 += a;
      if (yb) ((f32x2*)(yb + i0 * C128))[lane] = a + tc;
    }
  }

  const float invn = n > 0 ? 1.0f / (float)n : 0.0f;
  ((f32x2*)(meanp + (long long)wid * C128))[lane] = ((s0 + s1) + (s2 + s3)) * invn;
}

// One wave per cluster, both scales in one launch.
__global__ __launch_bounds__(256) void cluster_reduce2(
    const float* __restrict__ x0, const int* __restrict__ idx0,
    const int* __restrict__ off0, const int* __restrict__ cnt0,
    const float* __restrict__ t1, float* __restrict__ y0,
    float* __restrict__ mean0, int n1,
    const float* __restrict__ x1, const int* __restrict__ idx1,
    const int* __restrict__ off1, const int* __restrict__ cnt1,
    float* __restrict__ mean1, int n2)
{
  const int wid  = blockIdx.x * 4 + (threadIdx.x >> 6);
  const int lane = threadIdx.x & 63;
  if (wid >= n1 + n2) return;

  if (wid < n1)
    cr_one(wid, lane, x0, idx0, off0, cnt0,
           t1 + (long long)wid * C128, y0, mean0);
  else
    cr_one(wid - n1, lane, x1, idx1, off1, cnt1,
           nullptr, nullptr, mean1);
}

extern "C" void kernel_launch(void* const* d_in, const int* in_sizes, int n_in,
                              void* d_out, int out_size, void* d_ws, size_t ws_size,
                              hipStream_t stream)
{
  const float* x0 = (const float*)d_in[0];
  const float* x1 = (const float*)d_in[1];
  const float* x2 = (const float*)d_in[2];
  const int* cluster1 = (const int*)d_in[3];
  const int* cluster2 = (const int*)d_in[4];
  const float* Wf2c0 = (const float*)d_in[5];
  const float* Wf2c1 = (const float*)d_in[6];
  const float* Wc2f0 = (const float*)d_in[7];
  const float* Wc2f1 = (const float*)d_in[8];

  const int N0 = in_sizes[0] / C128;
  const int N1 = in_sizes[1] / C128;
  const int N2 = in_sizes[2] / C128;

  float* y0 = (float*)d_out;
  float* y1 = y0 + (long long)N0 * C128;
  float* y2 = y1 + (long long)N1 * C128;

  // means in-place in output regions (post_gemm is in-place safe)
  float* mean0 = y1;
  float* mean1 = y2;

  // ws: [t1: N1*128][t2: N2*128][cnt0: N1][cnt1: N2][tot: 2][off0: N1][off1: N2]
  //     [cur0: N1][cur1: N2][idx0: N0][idx1: N1]
  float* t1 = (float*)d_ws;
  float* t2 = t1 + (long long)N1 * C128;
  int* cnt0 = (int*)(t2 + (long long)N2 * C128);
  int* cnt1 = cnt0 + N1;
  int* tot  = cnt1 + N2;
  int* off0 = tot + 2;
  int* off1 = off0 + N1;
  int* cur0 = off1 + N2;
  int* cur1 = cur0 + N1;
  int* idx0 = cur1 + N2;
  int* idx1 = idx0 + N0;

  const int B1 = (N1 + 63) / 64;
  const int B2 = (N2 + 63) / 64;

  // 1. pre: zero cnt/cur/tot region + t1 = x1@Wc2f0^T, t2 = x2@Wc2f1^T
  pre_gemm<<<B1 + B2, 256, 0, stream>>>(
      x1, Wc2f0, t1, N1, x2, Wc2f1, t2, N2, cnt0, N1 + N2 + 2, B1);

  // 2-4. CSR build
  int bh = (N0 + N1 + 255) / 256; if (bh > 2048) bh = 2048;
  hist2<<<bh, 256, 0, stream>>>(cluster1, N0, cnt0, cluster2, N1, cnt1);
  const int p1 = (N1 + 255) & ~255, p2 = (N2 + 255) & ~255;
  scan2<<<(p1 + p2) / 256, 256, 0, stream>>>(
      cnt0, off0, cur0, N1, cnt1, off1, cur1, N2, tot);
  fill2<<<bh, 256, 0, stream>>>(cluster1, N0, cur0, idx0, cluster2, N1, cur1, idx1);

  // 5. fused gather: y0 = x0 + t1[cluster1], mean0, mean1 (one wave per cluster)
  cluster_reduce2<<<(N1 + N2 + 3) / 4, 256, 0, stream>>>(
      x0, idx0, off0, cnt0, t1, y0, mean0, N1,
      x1, idx1, off1, cnt1, mean1, N2);

  // 6. post: y1, y2
  post_gemm<<<B1 + B2, 256, 0, stream>>>(
      mean0, Wf2c0, x1, cluster2, t2, y1, N1,
      mean1, Wf2c1, x2, y2, N2, B1);
}

// Round 9
// 499.251 us; speedup vs baseline: 1.3679x; 1.0057x over previous
//
#include <hip/hip_runtime.h>

#define C128 128

typedef __attribute__((ext_vector_type(2))) float f32x2;
typedef __attribute__((ext_vector_type(4))) float f32x4;
typedef __attribute__((ext_vector_type(8))) short short8;

// f32 -> bf16 round-to-nearest-even (finite inputs)
__device__ __forceinline__ short f2bf(float f) {
  union { float f; unsigned u; } v; v.f = f;
  unsigned r = (v.u + 0x7fffu + ((v.u >> 16) & 1u)) >> 16;
  return (short)r;
}

// prep: zero counter region + convert all 4 Ws (128x128 f32) to bf16 once.
// Ws order in Wb: [Wc2f0][Wc2f1][Wf2c0][Wf2c1], each 16384 elements.
__global__ __launch_bounds__(256) void prep(
    const float* __restrict__ Wa, const float* __restrict__ Wb_,
    const float* __restrict__ Wc, const float* __restrict__ Wd,
    ushort* __restrict__ Wout, int* __restrict__ zbuf, int zlen)
{
  const int tid = blockIdx.x * 256 + threadIdx.x;
  const int nth = gridDim.x * 256;
  for (int k = tid; k < zlen; k += nth) zbuf[k] = 0;
  for (int k = tid; k < 4 * 16384; k += nth) {
    const float* W = (k < 16384) ? Wa : (k < 32768) ? Wb_ : (k < 49152) ? Wc : Wd;
    Wout[k] = (ushort)f2bf(W[k & 16383]);
  }
}

// out[r][j] = sum_k A[r][k]*W[j][k] (+add[r][j]) (+gtab[gidx[r]][j])
// W is PRE-CONVERTED global bf16 (32KB -> L1-resident per CU after warmup).
// One 64-row tile; 4 waves, wave owns 16 rows x 128 cols. MFMA 16x16x32 bf16.
// In-place safe for out==A (wave reads only the 16 rows it writes).
__device__ __forceinline__ void gemm_body(
    const float* __restrict__ A, const ushort* __restrict__ Wb,
    const float* __restrict__ add,
    const int* __restrict__ gidx, const float* __restrict__ gtab,
    float* __restrict__ out, int R, int blockrow)
{
  const int tid  = threadIdx.x;
  const int wave = tid >> 6;
  const int lane = tid & 63;
  const int r16  = lane & 15;
  const int kg   = lane >> 4;

  const int rowbase = blockrow + wave * 16;
  if (rowbase >= R) return;
  const int arow_i  = rowbase + r16;
  const int lrow    = arow_i < R ? arow_i : (R - 1);  // clamp; garbage never stored

  f32x4 acc[8];
#pragma unroll
  for (int i = 0; i < 8; ++i) acc[i] = (f32x4){0.f, 0.f, 0.f, 0.f};

  const float* arow = A + (long long)lrow * C128;

#pragma unroll
  for (int ks = 0; ks < 4; ++ks) {
    const int k0 = ks * 32 + kg * 8;
    f32x4 alo = *(const f32x4*)(arow + k0);
    f32x4 ahi = *(const f32x4*)(arow + k0 + 4);
    short8 af;
    af[0] = f2bf(alo.x); af[1] = f2bf(alo.y);
    af[2] = f2bf(alo.z); af[3] = f2bf(alo.w);
    af[4] = f2bf(ahi.x); af[5] = f2bf(ahi.y);
    af[6] = f2bf(ahi.z); af[7] = f2bf(ahi.w);
#pragma unroll
    for (int nf = 0; nf < 8; ++nf) {
      short8 bf = *(const short8*)(Wb + (nf * 16 + r16) * C128 + k0);
      acc[nf] = __builtin_amdgcn_mfma_f32_16x16x32_bf16(af, bf, acc[nf], 0, 0, 0);
    }
  }

#pragma unroll
  for (int i = 0; i < 4; ++i) {
    const int orow = rowbase + kg * 4 + i;
    if (orow >= R) continue;
    const float* addrow = add ? add + (long long)orow * C128 : nullptr;
    const float* grow = gidx ? gtab + (long long)gidx[orow] * C128 : nullptr;
    float* orow_p = out + (long long)orow * C128;
#pragma unroll
    for (int nf = 0; nf < 8; ++nf) {
      const int oc = nf * 16 + r16;
      float v = acc[nf][i];
      if (addrow) v += addrow[oc];
      if (grow)   v += grow[oc];
      orow_p[oc] = v;
    }
  }
}

// pre: histogram atomics (fire-and-forget, drain under the GEMM) + t1/t2 GEMMs
__global__ __launch_bounds__(256) void pre_hist_gemm(
    const float* __restrict__ x1, const ushort* __restrict__ W1b, float* __restrict__ t1, int n1,
    const float* __restrict__ x2, const ushort* __restrict__ W2b, float* __restrict__ t2, int n2,
    const int* __restrict__ cl1, int n0, int* __restrict__ cnt0,
    const int* __restrict__ cl2, int* __restrict__ cnt1, int B1)
{
  {
    int i = blockIdx.x * 256 + threadIdx.x;
    const int nth = gridDim.x * 256;
    const int total = n0 + n1;
    for (; i < total; i += nth) {
      if (i < n0) atomicAdd(&cnt0[cl1[i]], 1);
      else        atomicAdd(&cnt1[cl2[i - n0]], 1);
    }
  }
  if ((int)blockIdx.x < B1)
    gemm_body(x1, W1b, nullptr, nullptr, nullptr, t1, n1, blockIdx.x * 64);
  else
    gemm_body(x2, W2b, nullptr, nullptr, nullptr, t2, n2, (blockIdx.x - B1) * 64);
}

// post: y1 = mean0@Wf2c0^T + x1 + t2[cluster2] ; y2 = mean1@Wf2c1^T + x2 (in-place A==out)
__global__ __launch_bounds__(256) void post_gemm(
    const float* __restrict__ mean0, const ushort* __restrict__ Wab,
    const float* __restrict__ x1, const int* __restrict__ cluster2,
    const float* __restrict__ t2, float* __restrict__ y1, int n1,
    const float* __restrict__ mean1, const ushort* __restrict__ Wbb,
    const float* __restrict__ x2, float* __restrict__ y2, int n2, int B1)
{
  if ((int)blockIdx.x < B1)
    gemm_body(mean0, Wab, x1, cluster2, t2, y1, n1, blockIdx.x * 64);
  else
    gemm_body(mean1, Wbb, x2, nullptr, nullptr, y2, n2, (blockIdx.x - B1) * 64);
}

// merged offsets: wave-prefix-scan + one atomic per wave on the region cursor.
__global__ __launch_bounds__(256) void scan2(
    const int* __restrict__ cnt0, int* __restrict__ off0, int* __restrict__ cur0, int n1,
    const int* __restrict__ cnt1, int* __restrict__ off1, int* __restrict__ cur1, int n2,
    int* __restrict__ tot)
{
  const int p1 = (n1 + 255) & ~255;
  const int i  = blockIdx.x * blockDim.x + threadIdx.x;
  const int lane = threadIdx.x & 63;

  const int* cnt; int* off; int* cur; int* t; int j; int nn;
  if (i < p1) { cnt = cnt0; off = off0; cur = cur0; t = tot + 0; j = i;      nn = n1; }
  else        { cnt = cnt1; off = off1; cur = cur1; t = tot + 1; j = i - p1; nn = n2; }

  int c = (j < nn) ? cnt[j] : 0;
  int pref = c;
#pragma unroll
  for (int d = 1; d < 64; d <<= 1) {
    int v = __shfl_up(pref, d);
    if (lane >= d) pref += v;
  }
  const int wave_total = __shfl(pref, 63);
  int base = 0;
  if (lane == 63) base = atomicAdd(t, wave_total);
  base = __shfl(base, 63);

  if (j < nn) {
    const int o = base + (pref - c);
    off[j] = o;
    cur[j] = o;
  }
}

// merged member-list fill
__global__ __launch_bounds__(256) void fill2(
    const int* __restrict__ cl1, int n0, int* __restrict__ cur0, int* __restrict__ idx0,
    const int* __restrict__ cl2, int n1, int* __restrict__ cur1, int* __restrict__ idx1)
{
  int i = blockIdx.x * blockDim.x + threadIdx.x;
  const int stride = gridDim.x * blockDim.x;
  const int total = n0 + n1;
  for (; i < total; i += stride) {
    if (i < n0) { int p = atomicAdd(&cur0[cl1[i]], 1); idx0[p] = i; }
    else        { int k = i - n0; int p = atomicAdd(&cur1[cl2[k]], 1); idx1[p] = k; }
  }
}

// One cluster's fused gather: sum member rows (4 in flight), optional y-write,
// write mean. Lane owns columns {2*lane, 2*lane+1} (f32x2; 512B/row coalesced).
__device__ __forceinline__ void cr_one(
    int wid, int lane, const float* __restrict__ x,
    const int* __restrict__ idxp, const int* __restrict__ offp,
    const int* __restrict__ cntp, const float* __restrict__ trow,
    float* __restrict__ yb, float* __restrict__ meanp)
{
  const int n = cntp[wid];
  const int o = offp[wid];

  f32x2 tc = {0.f, 0.f};
  if (trow) tc = ((const f32x2*)trow)[lane];

  f32x2 s0 = {0.f,0.f}, s1 = {0.f,0.f}, s2 = {0.f,0.f}, s3 = {0.f,0.f};
  for (int base = 0; base < n; base += 64) {
    int m = n - base; if (m > 64) m = 64;
    int vi = (lane < m) ? idxp[o + base + lane] : 0;
    int j = 0;
    for (; j + 3 < m; j += 4) {
      const long long i0 = __shfl(vi, j);
      const long long i1 = __shfl(vi, j + 1);
      const long long i2 = __shfl(vi, j + 2);
      const long long i3 = __shfl(vi, j + 3);
      f32x2 a = ((const f32x2*)(x + i0 * C128))[lane];
      f32x2 b = ((const f32x2*)(x + i1 * C128))[lane];
      f32x2 c = ((const f32x2*)(x + i2 * C128))[lane];
      f32x2 d = ((const f32x2*)(x + i3 * C128))[lane];
      s0 += a; s1 += b; s2 += c; s3 += d;
      if (yb) {
        ((f32x2*)(yb + i0 * C128))[lane] = a + tc;
        ((f32x2*)(yb + i1 * C128))[lane] = b + tc;
        ((f32x2*)(yb + i2 * C128))[lane] = c + tc;
        ((f32x2*)(yb + i3 * C128))[lane] = d + tc;
      }
    }
    for (; j < m; ++j) {
      const long long i0 = __shfl(vi, j);
      f32x2 a = ((const f32x2*)(x + i0 * C128))[lane];
      s0 += a;
      if (yb) ((f32x2*)(yb + i0 * C128))[lane] = a + tc;
    }
  }

  const float invn = n > 0 ? 1.0f / (float)n : 0.0f;
  ((f32x2*)(meanp + (long long)wid * C128))[lane] = ((s0 + s1) + (s2 + s3)) * invn;
}

// One wave per cluster, both scales in one launch.
__global__ __launch_bounds__(256) void cluster_reduce2(
    const float* __restrict__ x0, const int* __restrict__ idx0,
    const int* __restrict__ off0, const int* __restrict__ cnt0,
    const float* __restrict__ t1, float* __restrict__ y0,
    float* __restrict__ mean0, int n1,
    const float* __restrict__ x1, const int* __restrict__ idx1,
    const int* __restrict__ off1, const int* __restrict__ cnt1,
    float* __restrict__ mean1, int n2)
{
  const int wid  = blockIdx.x * 4 + (threadIdx.x >> 6);
  const int lane = threadIdx.x & 63;
  if (wid >= n1 + n2) return;

  if (wid < n1)
    cr_one(wid, lane, x0, idx0, off0, cnt0,
           t1 + (long long)wid * C128, y0, mean0);
  else
    cr_one(wid - n1, lane, x1, idx1, off1, cnt1,
           nullptr, nullptr, mean1);
}

extern "C" void kernel_launch(void* const* d_in, const int* in_sizes, int n_in,
                              void* d_out, int out_size, void* d_ws, size_t ws_size,
                              hipStream_t stream)
{
  const float* x0 = (const float*)d_in[0];
  const float* x1 = (const float*)d_in[1];
  const float* x2 = (const float*)d_in[2];
  const int* cluster1 = (const int*)d_in[3];
  const int* cluster2 = (const int*)d_in[4];
  const float* Wf2c0 = (const float*)d_in[5];
  const float* Wf2c1 = (const float*)d_in[6];
  const float* Wc2f0 = (const float*)d_in[7];
  const float* Wc2f1 = (const float*)d_in[8];

  const int N0 = in_sizes[0] / C128;
  const int N1 = in_sizes[1] / C128;
  const int N2 = in_sizes[2] / C128;

  float* y0 = (float*)d_out;
  float* y1 = y0 + (long long)N0 * C128;
  float* y2 = y1 + (long long)N1 * C128;

  // means in-place in output regions (post_gemm is in-place safe)
  float* mean0 = y1;
  float* mean1 = y2;

  // ws: [t1: N1*128][t2: N2*128][cnt0: N1][cnt1: N2][tot: 2][off0: N1][off1: N2]
  //     [cur0: N1][cur1: N2][idx0: N0][idx1: N1][Wb: 4*16384 ushort]
  float* t1 = (float*)d_ws;
  float* t2 = t1 + (long long)N1 * C128;
  int* cnt0 = (int*)(t2 + (long long)N2 * C128);
  int* cnt1 = cnt0 + N1;
  int* tot  = cnt1 + N2;
  int* off0 = tot + 2;
  int* off1 = off0 + N1;
  int* cur0 = off1 + N2;
  int* cur1 = cur0 + N1;
  int* idx0 = cur1 + N2;
  int* idx1 = idx0 + N0;
  ushort* Wb = (ushort*)(idx1 + N1);
  ushort* Wb_c2f0 = Wb;                 // bf16 Wc2f0
  ushort* Wb_c2f1 = Wb + 16384;         // bf16 Wc2f1
  ushort* Wb_f2c0 = Wb + 32768;         // bf16 Wf2c0
  ushort* Wb_f2c1 = Wb + 49152;         // bf16 Wf2c1

  const int B1 = (N1 + 63) / 64;
  const int B2 = (N2 + 63) / 64;

  // 0. prep: zero counters + convert all Ws to bf16 (once)
  prep<<<256, 256, 0, stream>>>(
      Wc2f0, Wc2f1, Wf2c0, Wf2c1, Wb, cnt0, N1 + N2 + 2);

  // 1. pre: hist atomics (hidden under GEMM) + t1 = x1@Wc2f0^T, t2 = x2@Wc2f1^T
  pre_hist_gemm<<<B1 + B2, 256, 0, stream>>>(
      x1, Wb_c2f0, t1, N1, x2, Wb_c2f1, t2, N2,
      cluster1, N0, cnt0, cluster2, cnt1, B1);

  // 2-3. offsets + member lists
  const int p1 = (N1 + 255) & ~255, p2 = (N2 + 255) & ~255;
  scan2<<<(p1 + p2) / 256, 256, 0, stream>>>(
      cnt0, off0, cur0, N1, cnt1, off1, cur1, N2, tot);
  int bh = (N0 + N1 + 255) / 256; if (bh > 2048) bh = 2048;
  fill2<<<bh, 256, 0, stream>>>(cluster1, N0, cur0, idx0, cluster2, N1, cur1, idx1);

  // 4. fused gather: y0 = x0 + t1[cluster1], mean0, mean1 (one wave per cluster)
  cluster_reduce2<<<(N1 + N2 + 3) / 4, 256, 0, stream>>>(
      x0, idx0, off0, cnt0, t1, y0, mean0, N1,
      x1, idx1, off1, cnt1, mean1, N2);

  // 5. post: y1, y2
  post_gemm<<<B1 + B2, 256, 0, stream>>>(
      mean0, Wb_f2c0, x1, cluster2, t2, y1, N1,
      mean1, Wb_f2c1, x2, y2, N2, B1);
}